// Round 15
// baseline (484.329 us; speedup 1.0000x reference)
//
#include <hip/hip_runtime.h>
#include <math.h>

#define Nn 50000
#define Ee 600000
#define Bg 128      // batches (graphs)
#define Hd 128      // hidden dim
#define Kt 30       // sortpool K
#define CO 32       // conv out channels
#define KW 5        // conv kernel
#define LOUT 26     // K - KW + 1
#define CAP 2048    // per-batch node cap for topk LDS (max real count ~460)
#define SCB 196     // ceil(50000/256) scan blocks
#define GCB 782     // gcn blocks = ceil(50000/64)

typedef float v2f __attribute__((ext_vector_type(2)));
typedef short bf16x8 __attribute__((ext_vector_type(8)));
typedef float f32x4 __attribute__((ext_vector_type(4)));

// bf16 round-to-nearest-even helpers (branchless, finite inputs)
__device__ __forceinline__ unsigned short bfr(float v) {
    unsigned u = __builtin_bit_cast(unsigned, v);
    unsigned r = (u + 0x7FFFu + ((u >> 16) & 1u)) >> 16;
    return (unsigned short)r;
}
__device__ __forceinline__ float bff(unsigned short h) {
    unsigned u = ((unsigned)h) << 16;
    return __builtin_bit_cast(float, u);
}

// ---- count + batch starts + conv_w transpose + W 3-way split/pack ----------
// deg_i/cnt/bstart pre-set to -1 (0xFF memset). deg_i[c] ends at (#incoming - 1).
__global__ void countpack_kernel(const int* __restrict__ ei, const int* __restrict__ batch,
                            int* __restrict__ deg_i, int* __restrict__ bstart,
                            const float* __restrict__ conv_w, float* __restrict__ wT2,
                            const float* __restrict__ W0, const float* __restrict__ W1,
                            const float* __restrict__ W2,
                            ushort* __restrict__ Bph, ushort* __restrict__ Bpm,
                            ushort* __restrict__ Bpl) {
    int i = blockIdx.x * 256 + threadIdx.x;
    if (i < Ee) atomicAdd(&deg_i[ei[Ee + i]], 1);       // col = edge_index[1]
    if (i < Nn) {
        int b = batch[i];
        if (i == 0) bstart[b] = 0;
        else if (batch[i - 1] != b) bstart[b] = i;
    }
    if (i == 0) bstart[Bg] = Nn;
    if (i < CO * KW * Hd) {                     // wT2[o][k][ci] = conv_w[o][ci][k]
        int ci = i & 127;
        int r = i >> 7;          // o*KW + k
        int o = r / KW, k = r - o * KW;
        wT2[i] = conv_w[((size_t)o * Hd + ci) * KW + k];
    }
    if (i < 3 * 2048) {                          // W split+pack, B-fragment layout
        int l = i >> 11;
        int r = i & 2047;
        int kc = r >> 9;
        int n = (r >> 6) & 7;
        int lane = r & 63;
        int m = lane & 15, kq = lane >> 4;
        const float* W = (l == 0) ? W0 : (l == 1) ? W1 : W2;
        int col = n * 16 + m;
        size_t off = ((size_t)l * 2048 + (size_t)((kc * 8 + n) * 64 + lane)) * 8;
#pragma unroll
        for (int j = 0; j < 8; ++j) {
            float v = W[(size_t)(kc * 32 + kq * 8 + j) * Hd + col];
            unsigned short h = bfr(v);
            float r1 = v - bff(h);
            unsigned short mid = bfr(r1);
            Bph[off + j] = h;
            Bpm[off + j] = mid;
            Bpl[off + j] = bfr(r1 - bff(mid));
        }
    }
}

// ---- single scan dispatch: per-block direct offset sum + local scan + dinv --
__global__ __launch_bounds__(256) void scanBC2_kernel(const int* __restrict__ deg_i,
                            int* __restrict__ row_ptr, float* __restrict__ dinv,
                            int* __restrict__ bstart) {
    __shared__ int ls[256];
    __shared__ int boffS;
    int tid = threadIdx.x;
    int b = blockIdx.x;
    int s = 0;
    for (int k = 0; k < b; ++k)                 // j = k*256+tid < b*256 <= 49920 < Nn
        s += deg_i[k * 256 + tid] + 1;
    ls[tid] = s;
    __syncthreads();
    for (int off = 128; off > 0; off >>= 1) {
        if (tid < off) ls[tid] += ls[tid + off];
        __syncthreads();
    }
    if (tid == 0) boffS = ls[0];
    __syncthreads();
    int boff = boffS;
    int i = b * 256 + tid;
    int v2 = 0;
    if (i < Nn) {
        int raw = deg_i[i];
        v2 = raw + 1;                           // CSR row length (= #incoming)
        dinv[i] = 1.0f / sqrtf((float)(raw + 2));  // degree incl. self loop
    }
    ls[tid] = v2;
    __syncthreads();
    for (int off = 1; off < 256; off <<= 1) {
        int t = (tid >= off) ? ls[tid - off] : 0;
        __syncthreads();
        ls[tid] += t;
        __syncthreads();
    }
    if (i < Nn) row_ptr[i + 1] = ls[tid] + boff;
    if (i == 0) row_ptr[0] = 0;
    if (b == 0 && tid == 0) {   // empty batches inherit next start (batch sorted)
        for (int bb = Bg - 1; bb >= 0; --bb)
            if (bstart[bb] == -1) bstart[bb] = bstart[bb + 1];
    }
}

// ---------------- CSR fill (cnt pre-set to -1 by the 0xFF memset) ------------
__global__ void fill_kernel(const int* __restrict__ ei, const int* __restrict__ row_ptr,
                            int* __restrict__ cnt, int* __restrict__ csr_src) {
    int e = blockIdx.x * 256 + threadIdx.x;
    if (e >= Ee) return;
    int c = ei[Ee + e];
    int r = ei[e];
    int p = row_ptr[c] + atomicAdd(&cnt[c], 1) + 1;
    csr_src[p] = r;
}

// ---------------- fused GCN layer: gather (Âh) then MFMA (·W) + relu ---------
// Uses (Âh)W == Â(hW). Block = 64 nodes, 4 waves. Phase 1: each wave gathers
// 16 nodes (512 B full-row gathers = the proven agg pattern), result g =
// dinv[i]*(Σ src + self) into LDS (row stride 132 floats, 16B-aligned, ≤2-way
// bank alias). Phase 2: MFMA rows from LDS, 3-way split-bf16, epilogue
// relu(+bias), optional dinv post-scale (pre-scales the next layer's gather).
// scaleG: multiply gathered sources by dinv[s] (layer 0 only — x unscaled).
__global__ __launch_bounds__(256) void gcn_kernel(const float* __restrict__ hin,
                            const int* __restrict__ row_ptr, const int* __restrict__ csr_src,
                            const float* __restrict__ dinv, int scaleG,
                            const ushort* __restrict__ Bph, const ushort* __restrict__ Bpm,
                            const ushort* __restrict__ Bpl,
                            const float* __restrict__ bias, int scaleO,
                            float* __restrict__ hout) {
    __shared__ float gl[64][132];
    int tid = threadIdx.x, w = tid >> 6, lane = tid & 63;
    int nbase = blockIdx.x * 64;
    const v2f* hin2 = (const v2f*)hin;

    // ---- phase 1: gather 16 nodes per wave ----
    for (int p = 0; p < 16; ++p) {
        int nloc = w * 16 + p;
        int node = nbase + nloc;
        if (node < Nn) {
            float dn = dinv[node];
            v2f sv = hin2[(size_t)node * 64 + lane];
            v2f a0 = scaleG ? sv * dn : sv;      // self term
            v2f a1 = 0.f, a2 = 0.f, a3 = 0.f;
            int e = row_ptr[node], e1 = row_ptr[node + 1];
            if (scaleG) {
                for (; e + 3 < e1; e += 4) {
                    int s0 = __builtin_nontemporal_load(csr_src + e);
                    int s1 = __builtin_nontemporal_load(csr_src + e + 1);
                    int s2 = __builtin_nontemporal_load(csr_src + e + 2);
                    int s3 = __builtin_nontemporal_load(csr_src + e + 3);
                    float d0 = dinv[s0], d1 = dinv[s1], d2 = dinv[s2], d3 = dinv[s3];
                    a0 += hin2[(size_t)s0 * 64 + lane] * d0;
                    a1 += hin2[(size_t)s1 * 64 + lane] * d1;
                    a2 += hin2[(size_t)s2 * 64 + lane] * d2;
                    a3 += hin2[(size_t)s3 * 64 + lane] * d3;
                }
                for (; e < e1; ++e) {
                    int s0 = __builtin_nontemporal_load(csr_src + e);
                    a0 += hin2[(size_t)s0 * 64 + lane] * dinv[s0];
                }
            } else {
                for (; e + 3 < e1; e += 4) {
                    int s0 = __builtin_nontemporal_load(csr_src + e);
                    int s1 = __builtin_nontemporal_load(csr_src + e + 1);
                    int s2 = __builtin_nontemporal_load(csr_src + e + 2);
                    int s3 = __builtin_nontemporal_load(csr_src + e + 3);
                    a0 += hin2[(size_t)s0 * 64 + lane];
                    a1 += hin2[(size_t)s1 * 64 + lane];
                    a2 += hin2[(size_t)s2 * 64 + lane];
                    a3 += hin2[(size_t)s3 * 64 + lane];
                }
                for (; e < e1; ++e) {
                    int s0 = __builtin_nontemporal_load(csr_src + e);
                    a0 += hin2[(size_t)s0 * 64 + lane];
                }
            }
            v2f g = ((a0 + a1) + (a2 + a3)) * dn;
            gl[nloc][2 * lane] = g.x;
            gl[nloc][2 * lane + 1] = g.y;
        }
    }
    __syncthreads();

    // ---- phase 2: MFMA on the 64 gathered rows ----
    int m = lane & 15, kq = lane >> 4;
    f32x4 acc[8];
#pragma unroll
    for (int n = 0; n < 8; ++n) acc[n] = (f32x4)0.f;
    const float* ap = &gl[w * 16 + m][0];
#pragma unroll
    for (int kc = 0; kc < 4; ++kc) {
        float av[8];
        *(float4*)&av[0] = *(const float4*)(ap + kc * 32 + kq * 8);
        *(float4*)&av[4] = *(const float4*)(ap + kc * 32 + kq * 8 + 4);
        bf16x8 a0, a1, a2;
#pragma unroll
        for (int j = 0; j < 8; ++j) {
            unsigned short h = bfr(av[j]);
            float r1 = av[j] - bff(h);
            unsigned short mid = bfr(r1);
            a0[j] = (short)h;
            a1[j] = (short)mid;
            a2[j] = (short)bfr(r1 - bff(mid));
        }
        const ushort* bhp = Bph + (size_t)((kc * 8) * 64 + lane) * 8;
        const ushort* bmp = Bpm + (size_t)((kc * 8) * 64 + lane) * 8;
        const ushort* blp = Bpl + (size_t)((kc * 8) * 64 + lane) * 8;
#pragma unroll
        for (int n = 0; n < 8; ++n) {
            bf16x8 b0 = *(const bf16x8*)(bhp + (size_t)n * 64 * 8);
            bf16x8 b1 = *(const bf16x8*)(bmp + (size_t)n * 64 * 8);
            bf16x8 b2 = *(const bf16x8*)(blp + (size_t)n * 64 * 8);
            acc[n] = __builtin_amdgcn_mfma_f32_16x16x32_bf16(a0, b0, acc[n], 0, 0, 0);
            acc[n] = __builtin_amdgcn_mfma_f32_16x16x32_bf16(a1, b0, acc[n], 0, 0, 0);
            acc[n] = __builtin_amdgcn_mfma_f32_16x16x32_bf16(a0, b1, acc[n], 0, 0, 0);
            acc[n] = __builtin_amdgcn_mfma_f32_16x16x32_bf16(a1, b1, acc[n], 0, 0, 0);
            acc[n] = __builtin_amdgcn_mfma_f32_16x16x32_bf16(a2, b0, acc[n], 0, 0, 0);
            acc[n] = __builtin_amdgcn_mfma_f32_16x16x32_bf16(a0, b2, acc[n], 0, 0, 0);
        }
    }
    float bv[8];
#pragma unroll
    for (int n = 0; n < 8; ++n) bv[n] = bias[n * 16 + m];
    int rbase = nbase + w * 16 + kq * 4;
#pragma unroll
    for (int reg = 0; reg < 4; ++reg) {
        int r = rbase + reg;
        if (r < Nn) {
            float s = scaleO ? dinv[r] : 1.0f;
#pragma unroll
            for (int n = 0; n < 8; ++n) {
                float v = fmaxf(acc[n][reg] + bv[n], 0.f) * s;
                hout[(size_t)r * Hd + n * 16 + m] = v;
            }
        }
    }
}

// ---------------- fused tail (1024 thr): rank-select topk -> conv -> lin1 -> lin2 ----
__global__ __launch_bounds__(1024) void tail_kernel(const float* __restrict__ h,
                            const int* __restrict__ bstart,
                            const float* __restrict__ wT2, const float* __restrict__ conv_b,
                            const float* __restrict__ l1w, const float* __restrict__ l1b,
                            const float* __restrict__ l2w, const float* __restrict__ l2b,
                            float* __restrict__ out) {
    __shared__ float vals[CAP];          // 8 KB
    __shared__ float xcl[Kt][130];       // 15.6 KB, padded rows
    __shared__ float fl[CO * LOUT];      // 3.3 KB
    __shared__ float pz[8][Hd];          // 4 KB
    __shared__ float z[Hd];
    __shared__ int selS[Kt];
    int b = blockIdx.x, tid = threadIdx.x;

    int s0 = bstart[b], s1 = bstart[b + 1];
    int n = s1 - s0;
    int nc = n < CAP ? n : CAP;
    if (tid < Kt) selS[tid] = -1;
    for (int j = tid; j < nc; j += 1024)
        vals[j] = h[(size_t)(s0 + j) * Hd + (Hd - 1)];
    __syncthreads();

    // rank pass (descending value, tie: smaller index)
    for (int j = tid; j < nc; j += 1024) {
        float vj = vals[j];
        int rank = 0;
        for (int i = 0; i < nc; ++i) {          // i wave-uniform -> LDS broadcast
            float vi = vals[i];
            rank += (vi > vj || (vi == vj && i < j)) ? 1 : 0;
        }
        if (rank < Kt) selS[rank] = s0 + j;
    }
    __syncthreads();

    for (int i = tid; i < Kt * Hd; i += 1024) {
        int t = i >> 7, c = i & 127;
        int s = selS[t];
        xcl[t][c] = (s >= 0) ? h[(size_t)s * Hd + c] : 0.f;
    }
    __syncthreads();
    if (tid < CO * LOUT) {
        int o = tid / LOUT, t = tid - o * LOUT;
        float acc = conv_b[o];
#pragma unroll
        for (int k = 0; k < KW; ++k) {
            const float* xr = &xcl[t + k][0];
            const float* wr = wT2 + ((size_t)o * KW + k) * Hd;
#pragma unroll 8
            for (int c4 = 0; c4 < 32; ++c4) {
                float2 xa = *(const float2*)(xr + c4 * 4);
                float2 xb = *(const float2*)(xr + c4 * 4 + 2);
                float4 wv = *(const float4*)(wr + c4 * 4);
                acc = fmaf(xa.x, wv.x, acc);
                acc = fmaf(xa.y, wv.y, acc);
                acc = fmaf(xb.x, wv.z, acc);
                acc = fmaf(xb.y, wv.w, acc);
            }
        }
        fl[tid] = fmaxf(acc, 0.f);
    }
    __syncthreads();
    int hh = tid & 127, chunk = tid >> 7;
    int m0 = chunk * 104;
    float acc = 0.f;
    const float* lw = l1w + (size_t)m0 * Hd + hh;
#pragma unroll 8
    for (int m = 0; m < 104; ++m)
        acc = fmaf(fl[m0 + m], lw[(size_t)m * Hd], acc);
    pz[chunk][hh] = acc;
    __syncthreads();
    if (tid < Hd) {
        float a = l1b[tid];
#pragma unroll
        for (int q = 0; q < 8; ++q) a += pz[q][tid];
        z[tid] = fmaxf(a, 0.f);
    }
    __syncthreads();
    if (tid < 10) {
        float a2 = l2b[tid];
        for (int j = 0; j < Hd; ++j)
            a2 = fmaf(z[j], l2w[j * 10 + tid], a2);
        out[b * 10 + tid] = a2;
    }
}

extern "C" void kernel_launch(void* const* d_in, const int* in_sizes, int n_in,
                              void* d_out, int out_size, void* d_ws, size_t ws_size,
                              hipStream_t stream) {
    const float* x      = (const float*)d_in[0];
    const int*   ei     = (const int*)d_in[1];
    const int*   batch  = (const int*)d_in[2];
    const float* W0     = (const float*)d_in[3];
    const float* b0     = (const float*)d_in[4];
    const float* W1     = (const float*)d_in[5];
    const float* b1     = (const float*)d_in[6];
    const float* W2     = (const float*)d_in[7];
    const float* b2     = (const float*)d_in[8];
    const float* conv_w = (const float*)d_in[9];
    const float* conv_b = (const float*)d_in[10];
    const float* l1w    = (const float*)d_in[11];
    const float* l1b    = (const float*)d_in[12];
    const float* l2w    = (const float*)d_in[13];
    const float* l2b    = (const float*)d_in[14];
    float* out = (float*)d_out;

    // workspace layout — deg_i, cnt, bstart contiguous for one 0xFF memset
    int* wsI = (int*)d_ws;
    size_t off = 0;
    int*   deg_i   = wsI + off; off += Nn;
    int*   cnt     = wsI + off; off += Nn;
    int*   bstart  = wsI + off; off += 132;
    int*   row_ptr = wsI + off; off += 50004;
    float* dinv    = (float*)(wsI + off); off += Nn;
    int*   csr_src = wsI + off; off += Ee;
    off = (off + 3) & ~(size_t)3;        // 16B align
    ushort* Bph  = (ushort*)(wsI + off); off += 3 * 16384 / 2;   // packed W split hi
    ushort* Bpm  = (ushort*)(wsI + off); off += 3 * 16384 / 2;   // packed W split mid
    ushort* Bpl  = (ushort*)(wsI + off); off += 3 * 16384 / 2;   // packed W split lo
    float* hw    = (float*)(wsI + off); off += (size_t)Nn * Hd;
    float* hbuf  = (float*)(wsI + off); off += (size_t)Nn * Hd;
    float* wT2   = (float*)(wsI + off); off += CO * KW * Hd;

    // 1. set deg_i/cnt to -1, bstart to -1 sentinel (one DMA memset)
    hipMemsetAsync(deg_i, 0xFF, (size_t)(Nn + Nn + 132) * 4, stream);
    // 2. degree histogram + batch starts + W pack
    countpack_kernel<<<(Ee + 255) / 256, 256, 0, stream>>>(ei, batch, deg_i, bstart,
        conv_w, wT2, W0, W1, W2, Bph, Bpm, Bpl);
    // 3. single-dispatch scan: direct offset sum + local scan + dinv + bstart fix
    scanBC2_kernel<<<SCB, 256, 0, stream>>>(deg_i, row_ptr, dinv, bstart);
    // 4. CSR fill
    fill_kernel<<<(Ee + 255) / 256, 256, 0, stream>>>(ei, row_ptr, cnt, csr_src);
    // 5. three fused GCN layers: (Âh)W form — gather + MFMA in one kernel each
    gcn_kernel<<<GCB, 256, 0, stream>>>(x,    row_ptr, csr_src, dinv, 1,
        Bph,         Bpm,         Bpl,         b0, 1, hbuf);
    gcn_kernel<<<GCB, 256, 0, stream>>>(hbuf, row_ptr, csr_src, dinv, 0,
        Bph + 16384, Bpm + 16384, Bpl + 16384, b1, 1, hw);
    gcn_kernel<<<GCB, 256, 0, stream>>>(hw,   row_ptr, csr_src, dinv, 0,
        Bph + 32768, Bpm + 32768, Bpl + 32768, b2, 0, hbuf);
    // 6. fused tail: rank-topk + conv + lin1 + lin2
    tail_kernel<<<Bg, 1024, 0, stream>>>(hbuf, bstart, wT2, conv_b,
                                         l1w, l1b, l2w, l2b, out);
}